// Round 8
// baseline (369.976 us; speedup 1.0000x reference)
//
#include <hip/hip_runtime.h>

#define NN 2048   // atoms
#define CA 128    // c_atom
#define CR 389    // c_ref feature dim
#define CP 16     // c_atom_pair

typedef float nfloat4 __attribute__((ext_vector_type(4)));

// Grid: 2304 blocks = 256 groups of 9. In each group: r=0..7 -> plm row
// l = g*8+r; r==8 -> cl for atoms [g*8, g*8+8). Interleaving puts the
// read-heavy cl blocks throughout the write-heavy plm dispatch stream so
// they truly overlap (R4 paid cl serially; R5/R6 edge-placement = still
// serial). plm body = R4's empirically-best recipe: one row per block,
// thread=(pair p, channel-quad q), 1 KB contiguous nontemporal wave-stores.
__global__ __launch_bounds__(256) void fused_kernel(
    const float* __restrict__ pos, const float* __restrict__ charge,
    const float* __restrict__ mask, const float* __restrict__ elem,
    const float* __restrict__ names, const float* __restrict__ Wf,
    const float* __restrict__ bfeats,
    const int* __restrict__ uid,
    const float* __restrict__ Woff, const float* __restrict__ boff,
    const float* __restrict__ Winv, const float* __restrict__ binv,
    const float* __restrict__ Wvm, const float* __restrict__ bvm,
    float* __restrict__ cl, float* __restrict__ plm)
{
    __shared__ float ft[8][CR];
    const int tid = threadIdx.x;
    const int g = blockIdx.x / 9;
    const int r = blockIdx.x - g * 9;

    if (r < 8) {
        // ---------------- plm row l (R4 recipe) ----------------
        const int l = g * 8 + r;
        const int q = tid & 3;              // channel quad: channels 4q..4q+3
        const int p = tid >> 2;             // pair slot 0..63

        float w0[4], w1[4], w2[4], wi[4], kk[4];
        #pragma unroll
        for (int i = 0; i < 4; ++i) {
            int c = q * 4 + i;
            w0[i] = Woff[c];
            w1[i] = Woff[CP + c];
            w2[i] = Woff[2 * CP + c];
            wi[i] = Winv[c];
            kk[i] = Wvm[c] + boff[c] + binv[c] + bvm[c];
        }

        const float plx = pos[l * 3 + 0];
        const float ply = pos[l * 3 + 1];
        const float plz = pos[l * 3 + 2];
        const int ul = uid[l];
        nfloat4* __restrict__ dst = (nfloat4*)(plm + (size_t)l * NN * CP);

        #pragma unroll 4
        for (int j = 0; j < NN / 64; ++j) {   // 32 iterations, 64 pairs each
            const int m = j * 64 + p;
            const float dx = plx - pos[m * 3 + 0];
            const float dy = ply - pos[m * 3 + 1];
            const float dz = plz - pos[m * 3 + 2];
            const float inv = 1.0f / (1.0f + dx * dx + dy * dy + dz * dz);
            const unsigned sel = (uid[m] == ul) ? 0xFFFFFFFFu : 0u;

            float rx = fmaf(dx, w0[0], fmaf(dy, w1[0], fmaf(dz, w2[0], fmaf(inv, wi[0], kk[0]))));
            float ry = fmaf(dx, w0[1], fmaf(dy, w1[1], fmaf(dz, w2[1], fmaf(inv, wi[1], kk[1]))));
            float rz = fmaf(dx, w0[2], fmaf(dy, w1[2], fmaf(dz, w2[2], fmaf(inv, wi[2], kk[2]))));
            float rw = fmaf(dx, w0[3], fmaf(dy, w1[3], fmaf(dz, w2[3], fmaf(inv, wi[3], kk[3]))));

            nfloat4 rr;   // v==0 -> exact +0.0f via bitwise AND (every element written)
            rr.x = __uint_as_float(__float_as_uint(rx) & sel);
            rr.y = __uint_as_float(__float_as_uint(ry) & sel);
            rr.z = __uint_as_float(__float_as_uint(rz) & sel);
            rr.w = __uint_as_float(__float_as_uint(rw) & sel);

            __builtin_nontemporal_store(rr, dst + j * 256 + tid);  // 1 KB contiguous/wave
        }
    } else {
        // ---------------- cl: 8 atoms per group ----------------
        const int n0 = g * 8;

        // Stage concatenated features [pos(3),charge(1),mask(1),elem(128),names(256)]
        for (int idx = tid; idx < 8 * CR; idx += 256) {
            int a = idx / CR;
            int k = idx - a * CR;          // consecutive k -> coalesced elem/names
            int n = n0 + a;
            float v;
            if (k < 3)         v = pos[n * 3 + k];
            else if (k == 3)   v = charge[n];
            else if (k == 4)   v = mask[n];
            else if (k < 133)  v = elem[n * 128 + (k - 5)];
            else               v = names[n * 256 + (k - 133)];
            ft[a][k] = v;
        }
        __syncthreads();

        const int c = tid & 127;
        const int half = tid >> 7;          // atoms half*4 .. half*4+3
        float a0 = 0.f, a1 = 0.f, a2 = 0.f, a3 = 0.f;
        #pragma unroll 4                     // 4 Wf loads in flight, 4x reg reuse each
        for (int k = 0; k < CR; ++k) {
            const float w = Wf[k * CA + c];  // coalesced across c, L1/L2-resident
            a0 = fmaf(ft[half * 4 + 0][k], w, a0);   // LDS broadcast reads
            a1 = fmaf(ft[half * 4 + 1][k], w, a1);
            a2 = fmaf(ft[half * 4 + 2][k], w, a2);
            a3 = fmaf(ft[half * 4 + 3][k], w, a3);
        }
        const float bb = bfeats[c];
        const int nb = n0 + half * 4;
        cl[(size_t)(nb + 0) * CA + c] = a0 + bb;
        cl[(size_t)(nb + 1) * CA + c] = a1 + bb;
        cl[(size_t)(nb + 2) * CA + c] = a2 + bb;
        cl[(size_t)(nb + 3) * CA + c] = a3 + bb;
    }
}

extern "C" void kernel_launch(void* const* d_in, const int* in_sizes, int n_in,
                              void* d_out, int out_size, void* d_ws, size_t ws_size,
                              hipStream_t stream)
{
    const float* pos    = (const float*)d_in[0];
    const float* charge = (const float*)d_in[1];
    const float* mask   = (const float*)d_in[2];
    const float* elem   = (const float*)d_in[3];
    const float* names  = (const float*)d_in[4];
    const int*   uid    = (const int*)  d_in[5];
    const float* Wf     = (const float*)d_in[6];
    const float* bfeats = (const float*)d_in[7];
    const float* Woff   = (const float*)d_in[8];
    const float* boff   = (const float*)d_in[9];
    const float* Winv   = (const float*)d_in[10];
    const float* binv   = (const float*)d_in[11];
    const float* Wvm    = (const float*)d_in[12];
    const float* bvm    = (const float*)d_in[13];

    float* cl  = (float*)d_out;
    float* plm = (float*)d_out + (size_t)NN * CA;

    fused_kernel<<<256 * 9, 256, 0, stream>>>(
        pos, charge, mask, elem, names, Wf, bfeats, uid,
        Woff, boff, Winv, binv, Wvm, bvm, cl, plm);
}

// Round 9
// 337.323 us; speedup vs baseline: 1.0968x; 1.0968x over previous
//
#include <hip/hip_runtime.h>

#define NN 2048   // atoms
#define CA 128    // c_atom
#define CR 389    // c_ref feature dim
#define CP 16     // c_atom_pair

typedef float nfloat4 __attribute__((ext_vector_type(4)));

// ---------------- cl = concat(feats) @ W_feats + b_feats ----------------
// 256 blocks x 1024 threads. Thread = (atom a = tid>>7, channel c = tid&127).
__global__ __launch_bounds__(1024) void cl_kernel(
    const float* __restrict__ pos, const float* __restrict__ charge,
    const float* __restrict__ mask, const float* __restrict__ elem,
    const float* __restrict__ names, const float* __restrict__ Wf,
    const float* __restrict__ bfeats, float* __restrict__ cl)
{
    __shared__ float ft[8][CR];
    const int tid = threadIdx.x;
    const int n0 = blockIdx.x * 8;

    for (int idx = tid; idx < 8 * CR; idx += 1024) {
        int a = idx / CR;
        int k = idx - a * CR;          // consecutive k -> coalesced elem/names
        int n = n0 + a;
        float v;
        if (k < 3)         v = pos[n * 3 + k];
        else if (k == 3)   v = charge[n];
        else if (k == 4)   v = mask[n];
        else if (k < 133)  v = elem[n * 128 + (k - 5)];
        else               v = names[n * 256 + (k - 133)];
        ft[a][k] = v;
    }
    __syncthreads();

    const int c = tid & 127;
    const int a = tid >> 7;
    const float* fa = ft[a];
    float acc = 0.f;
    #pragma unroll 8
    for (int k = 0; k < CR; ++k)
        acc = fmaf(fa[k], Wf[k * CA + c], acc);

    __builtin_nontemporal_store(acc + bfeats[c], &cl[(size_t)(n0 + a) * CA + c]);
}

// ------- plm[l][m][c] = v * (dlm . Woff[:,c] + inv_sq*Winv[c] + K[c]) -------
// K[c] = Wvm[c]+boff[c]+binv[c]+bvm[c]  (v in {0,1}, v^2=v)
// One block per row l; thread t = (pair p = t>>2, channel-quad q = t&3).
// KEY CHANGE vs R4: all atom data staged in LDS as {x,y,z,uid} float4 (32 KB).
// Inner loop = 1 ds_read_b128 + ~30 VALU + 1 nontemporal 16B store -> the
// global-memory pipe sees a PURE store stream (fill-kernel-shaped; R4-R8
// issued 4-5 global loads per store on the same VMEM issue path).
__global__ __launch_bounds__(256) void plm_kernel(
    const float* __restrict__ pos, const int* __restrict__ uid,
    const float* __restrict__ Woff, const float* __restrict__ boff,
    const float* __restrict__ Winv, const float* __restrict__ binv,
    const float* __restrict__ Wvm, const float* __restrict__ bvm,
    float* __restrict__ plm)
{
    __shared__ float4 atom[NN];          // 32 KB: {x, y, z, uid bits}
    const int tid = threadIdx.x;

    for (int i = tid; i < NN; i += 256)  // one-time stage, ds_write_b128 2-way (free)
        atom[i] = make_float4(pos[3 * i], pos[3 * i + 1], pos[3 * i + 2],
                              __int_as_float(uid[i]));

    const int q = tid & 3;               // channel quad: channels 4q..4q+3
    float w0[4], w1[4], w2[4], wi[4], kk[4];
    #pragma unroll
    for (int i = 0; i < 4; ++i) {
        int c = q * 4 + i;
        w0[i] = Woff[c];
        w1[i] = Woff[CP + c];
        w2[i] = Woff[2 * CP + c];
        wi[i] = Winv[c];
        kk[i] = Wvm[c] + boff[c] + binv[c] + bvm[c];
    }
    __syncthreads();

    const int l = blockIdx.x;
    const float4 al = atom[l];           // broadcast read (free)
    const int p = tid >> 2;              // pair slot 0..63
    nfloat4* __restrict__ dst = (nfloat4*)(plm + (size_t)l * NN * CP);

    #pragma unroll 4
    for (int j = 0; j < NN / 64; ++j) {  // 32 iters; 1 ds_read + 1 store each
        const float4 am = atom[j * 64 + p];   // quad-broadcast, 2-way banks (free)
        const float dx = al.x - am.x;
        const float dy = al.y - am.y;
        const float dz = al.z - am.z;
        const float inv = __builtin_amdgcn_rcpf(1.0f + dx * dx + dy * dy + dz * dz);
        const unsigned sel =
            (__float_as_uint(al.w) == __float_as_uint(am.w)) ? 0xFFFFFFFFu : 0u;

        float rx = fmaf(dx, w0[0], fmaf(dy, w1[0], fmaf(dz, w2[0], fmaf(inv, wi[0], kk[0]))));
        float ry = fmaf(dx, w0[1], fmaf(dy, w1[1], fmaf(dz, w2[1], fmaf(inv, wi[1], kk[1]))));
        float rz = fmaf(dx, w0[2], fmaf(dy, w1[2], fmaf(dz, w2[2], fmaf(inv, wi[2], kk[2]))));
        float rw = fmaf(dx, w0[3], fmaf(dy, w1[3], fmaf(dz, w2[3], fmaf(inv, wi[3], kk[3]))));

        nfloat4 rr;   // v==0 -> exact +0.0f via bitwise AND (every element written)
        rr.x = __uint_as_float(__float_as_uint(rx) & sel);
        rr.y = __uint_as_float(__float_as_uint(ry) & sel);
        rr.z = __uint_as_float(__float_as_uint(rz) & sel);
        rr.w = __uint_as_float(__float_as_uint(rw) & sel);

        __builtin_nontemporal_store(rr, dst + j * 256 + tid);  // 1 KB contiguous/wave
    }
}

extern "C" void kernel_launch(void* const* d_in, const int* in_sizes, int n_in,
                              void* d_out, int out_size, void* d_ws, size_t ws_size,
                              hipStream_t stream)
{
    const float* pos    = (const float*)d_in[0];
    const float* charge = (const float*)d_in[1];
    const float* mask   = (const float*)d_in[2];
    const float* elem   = (const float*)d_in[3];
    const float* names  = (const float*)d_in[4];
    const int*   uid    = (const int*)  d_in[5];
    const float* Wf     = (const float*)d_in[6];
    const float* bfeats = (const float*)d_in[7];
    const float* Woff   = (const float*)d_in[8];
    const float* boff   = (const float*)d_in[9];
    const float* Winv   = (const float*)d_in[10];
    const float* binv   = (const float*)d_in[11];
    const float* Wvm    = (const float*)d_in[12];
    const float* bvm    = (const float*)d_in[13];

    float* cl  = (float*)d_out;
    float* plm = (float*)d_out + (size_t)NN * CA;

    cl_kernel<<<NN / 8, 1024, 0, stream>>>(pos, charge, mask, elem, names, Wf, bfeats, cl);
    plm_kernel<<<NN, 256, 0, stream>>>(pos, uid, Woff, boff, Winv, binv, Wvm, bvm, plm);
}